// Round 1
// baseline (365.694 us; speedup 1.0000x reference)
//
#include <hip/hip_runtime.h>

// Quaternion max-amplitude 2x2 pool.
// x: (16, 256, 128, 128) fp32 -> out: (16, 256, 64, 64) fp32
// channels = 4 quaternion components x 64.
// For each (b, c4, oh, ow): amp2[kk] = sum_q x[b, q*64+c4, 2oh+kh, 2ow+kw]^2,
// kk = kh*2+kw; pick first argmax kk; emit all 4 components at that kk.

#define IN_H 128
#define IN_W 128
#define C4   64
#define OUT_H 64
#define OUT_W 64

__global__ __launch_bounds__(256) void qpool_kernel(const float* __restrict__ x,
                                                    float* __restrict__ out) {
    // total threads = 16 * 64 * 64 * 32 = 2097152
    // each thread handles 2 adjacent output columns (one float4 of input per row)
    int tid = blockIdx.x * blockDim.x + threadIdx.x;
    int ow2 = tid & 31;          // float4 group: covers ow = 2*ow2, 2*ow2+1
    int oh  = (tid >> 5) & 63;
    int c4i = (tid >> 11) & 63;
    int b   = tid >> 17;

    const long in_ch_stride = (long)IN_H * IN_W;        // 16384
    const long in_b_stride  = 256L * in_ch_stride;
    const float* base = x + (long)b * in_b_stride + (long)c4i * in_ch_stride
                          + (long)(2 * oh) * IN_W + 4 * ow2;

    // arr[q][kh][col]  col in 0..3 (input columns 4*ow2 .. 4*ow2+3)
    float arr[4][2][4];
    #pragma unroll
    for (int q = 0; q < 4; ++q) {
        const float* p = base + (long)q * C4 * in_ch_stride;
        float4 r0 = *(const float4*)(p);
        float4 r1 = *(const float4*)(p + IN_W);
        arr[q][0][0] = r0.x; arr[q][0][1] = r0.y; arr[q][0][2] = r0.z; arr[q][0][3] = r0.w;
        arr[q][1][0] = r1.x; arr[q][1][1] = r1.y; arr[q][1][2] = r1.z; arr[q][1][3] = r1.w;
    }

    float res[4][2];  // [q][slot]
    #pragma unroll
    for (int s = 0; s < 2; ++s) {
        // window columns for this output slot: 2*s + kw
        float amp[4];
        #pragma unroll
        for (int kk = 0; kk < 4; ++kk) {
            const int kh = kk >> 1, kw = kk & 1;
            float sum = 0.f;
            #pragma unroll
            for (int q = 0; q < 4; ++q) {
                float t = arr[q][kh][2 * s + kw];
                sum += t * t;
            }
            amp[kk] = sum;
        }
        // first-occurrence argmax (strict >): matches jnp.argmax
        int best = 0;
        float bv = amp[0];
        #pragma unroll
        for (int kk = 1; kk < 4; ++kk) {
            if (amp[kk] > bv) { bv = amp[kk]; best = kk; }
        }
        #pragma unroll
        for (int q = 0; q < 4; ++q) {
            float r = arr[q][0][2 * s + 0];
            r = (best == 1) ? arr[q][0][2 * s + 1] : r;
            r = (best == 2) ? arr[q][1][2 * s + 0] : r;
            r = (best == 3) ? arr[q][1][2 * s + 1] : r;
            res[q][s] = r;
        }
    }

    const long out_ch_stride = (long)OUT_H * OUT_W;     // 4096
    const long out_b_stride  = 256L * out_ch_stride;
    float* obase = out + (long)b * out_b_stride + (long)c4i * out_ch_stride
                       + (long)oh * OUT_W + 2 * ow2;
    #pragma unroll
    for (int q = 0; q < 4; ++q) {
        float2 w;
        w.x = res[q][0];
        w.y = res[q][1];
        *(float2*)(obase + (long)q * C4 * out_ch_stride) = w;
    }
}

extern "C" void kernel_launch(void* const* d_in, const int* in_sizes, int n_in,
                              void* d_out, int out_size, void* d_ws, size_t ws_size,
                              hipStream_t stream) {
    const float* x = (const float*)d_in[0];
    float* out = (float*)d_out;
    // threads: 16 * 64 * 64 * 32 = 2097152; blocks = 8192
    const int total = 16 * 64 * 64 * 32;
    const int block = 256;
    const int grid = total / block;
    qpool_kernel<<<grid, block, 0, stream>>>(x, out);
}